// Round 1
// baseline (1083.347 us; speedup 1.0000x reference)
//
#include <hip/hip_runtime.h>
#include <math.h>

#define SCAN_BLOCK 256
#define SCAN_ELEMS 1024  // 4 per thread

// ---------------- degree count ----------------
__global__ void k_count(const int* __restrict__ dst, int E, int* __restrict__ counts) {
    int e = blockIdx.x * blockDim.x + threadIdx.x;
    if (e < E) atomicAdd(&counts[dst[e]], 1);
}

__global__ void k_dinv(const int* __restrict__ counts, int N, float* __restrict__ dinv) {
    int i = blockIdx.x * blockDim.x + threadIdx.x;
    if (i < N) dinv[i] = rsqrtf((float)counts[i] + 1.0f);
}

// ---------------- exclusive scan (3 kernels) ----------------
__global__ void k_scan1(const int* __restrict__ counts, int N,
                        int* __restrict__ offsets, int* __restrict__ blockSums) {
    __shared__ int sdata[SCAN_BLOCK];
    int t = threadIdx.x;
    int base = blockIdx.x * SCAN_ELEMS;
    int idx0 = base + t * 4;
    int v[4];
    int sum = 0;
#pragma unroll
    for (int j = 0; j < 4; j++) {
        int idx = idx0 + j;
        v[j] = (idx < N) ? counts[idx] : 0;
        sum += v[j];
    }
    sdata[t] = sum;
    __syncthreads();
    for (int off = 1; off < SCAN_BLOCK; off <<= 1) {
        int tmp = (t >= off) ? sdata[t - off] : 0;
        __syncthreads();
        sdata[t] += tmp;
        __syncthreads();
    }
    int run = (t > 0) ? sdata[t - 1] : 0;
#pragma unroll
    for (int j = 0; j < 4; j++) {
        int idx = idx0 + j;
        if (idx < N) offsets[idx] = run;
        run += v[j];
    }
    if (t == SCAN_BLOCK - 1) blockSums[blockIdx.x] = sdata[t];
}

__global__ void k_scan2(const int* __restrict__ blockSums, int nb, int* __restrict__ blockOffsets) {
    __shared__ int sdata[SCAN_BLOCK];
    int t = threadIdx.x;
    sdata[t] = (t < nb) ? blockSums[t] : 0;
    __syncthreads();
    for (int off = 1; off < SCAN_BLOCK; off <<= 1) {
        int tmp = (t >= off) ? sdata[t - off] : 0;
        __syncthreads();
        sdata[t] += tmp;
        __syncthreads();
    }
    if (t < nb) blockOffsets[t] = (t > 0) ? sdata[t - 1] : 0;
    if (t == nb - 1) blockOffsets[nb] = sdata[t];  // total
}

__global__ void k_scan3(int* __restrict__ offsets, int N,
                        const int* __restrict__ blockOffsets, int nb) {
    int i = blockIdx.x * blockDim.x + threadIdx.x;
    if (i < N) offsets[i] += blockOffsets[i / SCAN_ELEMS];
    if (i == 0) offsets[N] = blockOffsets[nb];
}

// ---------------- edge scatter into dst-sorted CSR ----------------
__global__ void k_scatter(const int* __restrict__ src, const int* __restrict__ dst, int E,
                          const int* __restrict__ offsets, int* __restrict__ cursor,
                          int* __restrict__ sorted_src) {
    int e = blockIdx.x * blockDim.x + threadIdx.x;
    if (e < E) {
        int d = dst[e];
        int pos = offsets[d] + atomicAdd(&cursor[d], 1);
        sorted_src[pos] = src[e];
    }
}

// ---------------- aggregation: out[i] = dinv[i]*(sum_{e} dinv[s]*feat[s] + dinv[i]*feat[i])
// one wave per node, lane = feature (64 features)
__global__ __launch_bounds__(256) void k_agg(const float* __restrict__ feat,
                                             const float* __restrict__ dinv,
                                             const int* __restrict__ offsets,
                                             const int* __restrict__ sorted_src,
                                             int N, float* __restrict__ out) {
    int wid = threadIdx.x >> 6;
    int lane = threadIdx.x & 63;
    int i = blockIdx.x * 4 + wid;
    if (i >= N) return;
    int beg = offsets[i], end = offsets[i + 1];
    float di = dinv[i];
    float acc = 0.f;
    int e = beg;
    for (; e + 1 < end; e += 2) {
        int s0 = sorted_src[e];
        int s1 = sorted_src[e + 1];
        float w0 = dinv[s0], w1 = dinv[s1];
        float f0 = feat[(size_t)s0 * 64 + lane];
        float f1 = feat[(size_t)s1 * 64 + lane];
        acc += w0 * f0 + w1 * f1;
    }
    if (e < end) {
        int s0 = sorted_src[e];
        acc += dinv[s0] * feat[(size_t)s0 * 64 + lane];
    }
    acc += di * feat[(size_t)i * 64 + lane];
    out[(size_t)i * 64 + lane] = acc * di;
}

// ---------------- layer-2 aggregation fused with bias + row L2-normalize; writes final embeddings
__global__ __launch_bounds__(256) void k_agg2(const float* __restrict__ g,
                                              const float* __restrict__ dinv,
                                              const int* __restrict__ offsets,
                                              const int* __restrict__ sorted_src,
                                              const float* __restrict__ b2,
                                              int N, float* __restrict__ finalOut) {
    int wid = threadIdx.x >> 6;
    int lane = threadIdx.x & 63;
    int i = blockIdx.x * 4 + wid;
    if (i >= N) return;
    int beg = offsets[i], end = offsets[i + 1];
    float di = dinv[i];
    float acc = 0.f;
    int e = beg;
    for (; e + 1 < end; e += 2) {
        int s0 = sorted_src[e];
        int s1 = sorted_src[e + 1];
        float w0 = dinv[s0], w1 = dinv[s1];
        float f0 = g[(size_t)s0 * 64 + lane];
        float f1 = g[(size_t)s1 * 64 + lane];
        acc += w0 * f0 + w1 * f1;
    }
    if (e < end) {
        int s0 = sorted_src[e];
        acc += dinv[s0] * g[(size_t)s0 * 64 + lane];
    }
    acc += di * g[(size_t)i * 64 + lane];
    float z = acc * di + b2[lane];
    float sq = z * z;
#pragma unroll
    for (int m = 32; m >= 1; m >>= 1) sq += __shfl_xor(sq, m, 64);
    float nrm = sqrtf(sq);
    finalOut[(size_t)i * 64 + lane] = z / (nrm + 1e-12f);
}

// ---------------- fp32 GEMM: out[N x OUT] = A[N x K] @ W[K x OUT] (+bias) (optional relu)
template <int K, int OUT>
__global__ __launch_bounds__(256) void k_gemm(const float* __restrict__ A,
                                              const float* __restrict__ W,
                                              const float* __restrict__ bias,
                                              float* __restrict__ out, int N, int do_relu) {
    constexpr int RPI = 256 / OUT;  // rows per iteration
    constexpr int ROWS = 32;
    __shared__ float Wl[K * OUT];
    __shared__ float bl[OUT];
    __shared__ float rowbuf[RPI * K];
    int t = threadIdx.x;
    for (int idx = t; idx < K * OUT / 4; idx += 256)
        ((float4*)Wl)[idx] = ((const float4*)W)[idx];
    for (int idx = t; idx < OUT; idx += 256) bl[idx] = bias ? bias[idx] : 0.f;
    __syncthreads();
    int r0 = blockIdx.x * ROWS;
    int c = t % OUT;
    int rr = t / OUT;
    for (int it = 0; it < ROWS / RPI; it++) {
        int rbase = r0 + it * RPI;
        __syncthreads();
        for (int idx = t; idx < RPI * K / 4; idx += 256) {
            int elem = idx * 4;
            int r = elem / K;
            int k = elem % K;
            int row = rbase + r;
            float4 v = (row < N) ? ((const float4*)A)[(size_t)row * (K / 4) + k / 4]
                                 : make_float4(0.f, 0.f, 0.f, 0.f);
            ((float4*)rowbuf)[idx] = v;
        }
        __syncthreads();
        int row = rbase + rr;
        float acc = 0.f;
#pragma unroll 8
        for (int k = 0; k < K; k++) acc = fmaf(rowbuf[rr * K + k], Wl[k * OUT + c], acc);
        acc += bl[c];
        if (do_relu) acc = fmaxf(acc, 0.f);
        if (row < N) out[(size_t)row * OUT + c] = acc;
    }
}

// ---------------- decoder GEMM (64->256) fused with log_softmax
__global__ __launch_bounds__(256) void k_dec(const float* __restrict__ F,
                                             const float* __restrict__ Wd,
                                             const float* __restrict__ bd,
                                             int N, float* __restrict__ out) {
    __shared__ float Wl[64 * 256];  // 64 KB
    __shared__ float bl[256];
    int t = threadIdx.x;
    for (int idx = t; idx < 64 * 256 / 4; idx += 256)
        ((float4*)Wl)[idx] = ((const float4*)Wd)[idx];
    if (t < 256) bl[t] = bd[t];
    __syncthreads();
    int wid = t >> 6, lane = t & 63;
    int nTasks = (N + 3) / 4;
    int stride = gridDim.x * 4;
    for (int task = blockIdx.x * 4 + wid; task < nTasks; task += stride) {
        int r0 = task * 4;
        float v[4];
#pragma unroll
        for (int j = 0; j < 4; j++)
            v[j] = (r0 + j < N) ? F[(size_t)(r0 + j) * 64 + lane] : 0.f;
        float acc[4][4];
#pragma unroll
        for (int j = 0; j < 4; j++)
#pragma unroll
            for (int q = 0; q < 4; q++) acc[j][q] = 0.f;
        for (int k = 0; k < 64; k++) {
            float4 w4 = ((const float4*)Wl)[k * 64 + lane];
#pragma unroll
            for (int j = 0; j < 4; j++) {
                float fk = __shfl(v[j], k, 64);
                acc[j][0] = fmaf(fk, w4.x, acc[j][0]);
                acc[j][1] = fmaf(fk, w4.y, acc[j][1]);
                acc[j][2] = fmaf(fk, w4.z, acc[j][2]);
                acc[j][3] = fmaf(fk, w4.w, acc[j][3]);
            }
        }
        float4 b4 = ((const float4*)bl)[lane];
#pragma unroll
        for (int j = 0; j < 4; j++) {
            int row = r0 + j;
            if (row >= N) break;
            float a0 = acc[j][0] + b4.x;
            float a1 = acc[j][1] + b4.y;
            float a2 = acc[j][2] + b4.z;
            float a3 = acc[j][3] + b4.w;
            float m = fmaxf(fmaxf(a0, a1), fmaxf(a2, a3));
#pragma unroll
            for (int mm = 32; mm >= 1; mm >>= 1) m = fmaxf(m, __shfl_xor(m, mm, 64));
            float s = __expf(a0 - m) + __expf(a1 - m) + __expf(a2 - m) + __expf(a3 - m);
#pragma unroll
            for (int mm = 32; mm >= 1; mm >>= 1) s += __shfl_xor(s, mm, 64);
            float lz = m + __logf(s);
            float4 o = make_float4(a0 - lz, a1 - lz, a2 - lz, a3 - lz);
            ((float4*)out)[(size_t)row * 64 + lane] = o;
        }
    }
}

extern "C" void kernel_launch(void* const* d_in, const int* in_sizes, int n_in,
                              void* d_out, int out_size, void* d_ws, size_t ws_size,
                              hipStream_t stream) {
    const float* x = (const float*)d_in[0];
    const int* ei = (const int*)d_in[1];
    const float* W1 = (const float*)d_in[2];
    const float* b1 = (const float*)d_in[3];
    const float* W2 = (const float*)d_in[4];
    const float* b2 = (const float*)d_in[5];
    const float* Wd = (const float*)d_in[6];
    const float* bd = (const float*)d_in[7];
    int N = in_sizes[0] / 64;
    int E = in_sizes[1] / 2;
    const int* srcIdx = ei;
    const int* dstIdx = ei + E;

    char* w = (char*)d_ws;
    auto alloc = [&](size_t bytes) {
        void* p = (void*)w;
        w += (bytes + 255) & ~(size_t)255;
        return p;
    };
    int* counts = (int*)alloc((size_t)N * 4);
    int* cursor = (int*)alloc((size_t)N * 4);
    int* offsets = (int*)alloc((size_t)(N + 1) * 4);
    int* blockSums = (int*)alloc(4096);
    int* blockOffsets = (int*)alloc(4096);
    int* sorted_src = (int*)alloc((size_t)E * 4);
    float* dinv = (float*)alloc((size_t)N * 4);
    float* z1 = (float*)alloc((size_t)N * 64 * 4);   // reused as g = h1@W2
    float* h1 = (float*)alloc((size_t)N * 128 * 4);
    float* outLogp = (float*)d_out;
    float* outFinal = (float*)d_out + (size_t)N * 256;

    hipMemsetAsync(counts, 0, (size_t)N * 4, stream);
    hipMemsetAsync(cursor, 0, (size_t)N * 4, stream);

    k_count<<<(E + 255) / 256, 256, 0, stream>>>(dstIdx, E, counts);
    k_dinv<<<(N + 255) / 256, 256, 0, stream>>>(counts, N, dinv);

    int nb = (N + SCAN_ELEMS - 1) / SCAN_ELEMS;
    k_scan1<<<nb, SCAN_BLOCK, 0, stream>>>(counts, N, offsets, blockSums);
    k_scan2<<<1, SCAN_BLOCK, 0, stream>>>(blockSums, nb, blockOffsets);
    k_scan3<<<(N + 255) / 256, 256, 0, stream>>>(offsets, N, blockOffsets, nb);
    k_scatter<<<(E + 255) / 256, 256, 0, stream>>>(srcIdx, dstIdx, E, offsets, cursor, sorted_src);

    // layer 1: z1 = A_hat @ x  (64 feat), then h1 = relu(z1@W1 + b1)
    k_agg<<<(N + 3) / 4, 256, 0, stream>>>(x, dinv, offsets, sorted_src, N, z1);
    k_gemm<64, 128><<<(N + 31) / 32, 256, 0, stream>>>(z1, W1, b1, h1, N, 1);

    // layer 2: g = h1@W2 (64 feat), then z2 = A_hat @ g + b2, row-normalize -> final
    k_gemm<128, 64><<<(N + 31) / 32, 256, 0, stream>>>(h1, W2, nullptr, z1, N, 0);
    k_agg2<<<(N + 3) / 4, 256, 0, stream>>>(z1, dinv, offsets, sorted_src, b2, N, outFinal);

    // decoder + log_softmax
    k_dec<<<2048, 256, 0, stream>>>(outFinal, Wd, bd, N, outLogp);
}

// Round 2
// 860.044 us; speedup vs baseline: 1.2596x; 1.2596x over previous
//
#include <hip/hip_runtime.h>
#include <math.h>

#define SCAN_BLOCK 256
#define SCAN_ELEMS 1024  // 4 per thread

// ---- bf16 helpers (RNE) ----
__device__ __forceinline__ float bf2f(unsigned short u) {
    union { unsigned int i; float f; } v;
    v.i = ((unsigned int)u) << 16;
    return v.f;
}
__device__ __forceinline__ unsigned short f2bf(float f) {
    union { float f; unsigned int i; } v;
    v.f = f;
    unsigned int r = v.i + 0x7FFF + ((v.i >> 16) & 1);
    return (unsigned short)(r >> 16);
}

// ---------------- degree count ----------------
__global__ void k_count(const int* __restrict__ dst, int E, int* __restrict__ counts) {
    int e = blockIdx.x * blockDim.x + threadIdx.x;
    if (e < E) atomicAdd(&counts[dst[e]], 1);
}

__global__ void k_dinv(const int* __restrict__ counts, int N, float* __restrict__ dinv) {
    int i = blockIdx.x * blockDim.x + threadIdx.x;
    if (i < N) dinv[i] = rsqrtf((float)counts[i] + 1.0f);
}

// xsc[i][f] = bf16(dinv[i] * x[i][f]); one thread per float4
__global__ void k_prep(const float* __restrict__ x, const float* __restrict__ dinv,
                       int N, unsigned short* __restrict__ xsc) {
    int i = blockIdx.x * blockDim.x + threadIdx.x;  // over N*16 float4s
    if (i >= N * 16) return;
    int node = i >> 4;
    float d = dinv[node];
    float4 v = ((const float4*)x)[i];
    ushort4 u;
    u.x = f2bf(v.x * d);
    u.y = f2bf(v.y * d);
    u.z = f2bf(v.z * d);
    u.w = f2bf(v.w * d);
    ((ushort4*)xsc)[i] = u;
}

// ---------------- exclusive scan (3 kernels) ----------------
__global__ void k_scan1(const int* __restrict__ counts, int N,
                        int* __restrict__ offsets, int* __restrict__ blockSums) {
    __shared__ int sdata[SCAN_BLOCK];
    int t = threadIdx.x;
    int base = blockIdx.x * SCAN_ELEMS;
    int idx0 = base + t * 4;
    int v[4];
    int sum = 0;
#pragma unroll
    for (int j = 0; j < 4; j++) {
        int idx = idx0 + j;
        v[j] = (idx < N) ? counts[idx] : 0;
        sum += v[j];
    }
    sdata[t] = sum;
    __syncthreads();
    for (int off = 1; off < SCAN_BLOCK; off <<= 1) {
        int tmp = (t >= off) ? sdata[t - off] : 0;
        __syncthreads();
        sdata[t] += tmp;
        __syncthreads();
    }
    int run = (t > 0) ? sdata[t - 1] : 0;
#pragma unroll
    for (int j = 0; j < 4; j++) {
        int idx = idx0 + j;
        if (idx < N) offsets[idx] = run;
        run += v[j];
    }
    if (t == SCAN_BLOCK - 1) blockSums[blockIdx.x] = sdata[t];
}

__global__ void k_scan2(const int* __restrict__ blockSums, int nb, int* __restrict__ blockOffsets) {
    __shared__ int sdata[SCAN_BLOCK];
    int t = threadIdx.x;
    sdata[t] = (t < nb) ? blockSums[t] : 0;
    __syncthreads();
    for (int off = 1; off < SCAN_BLOCK; off <<= 1) {
        int tmp = (t >= off) ? sdata[t - off] : 0;
        __syncthreads();
        sdata[t] += tmp;
        __syncthreads();
    }
    if (t < nb) blockOffsets[t] = (t > 0) ? sdata[t - 1] : 0;
    if (t == nb - 1) blockOffsets[nb] = sdata[t];  // total
}

__global__ void k_scan3(int* __restrict__ offsets, int N,
                        const int* __restrict__ blockOffsets, int nb) {
    int i = blockIdx.x * blockDim.x + threadIdx.x;
    if (i < N) offsets[i] += blockOffsets[i / SCAN_ELEMS];
    if (i == 0) offsets[N] = blockOffsets[nb];
}

// ---------------- edge scatter into dst-sorted CSR ----------------
__global__ void k_scatter(const int* __restrict__ src, const int* __restrict__ dst, int E,
                          const int* __restrict__ offsets, int* __restrict__ cursor,
                          int* __restrict__ sorted_src) {
    int e = blockIdx.x * blockDim.x + threadIdx.x;
    if (e < E) {
        int d = dst[e];
        int pos = offsets[d] + atomicAdd(&cursor[d], 1);
        sorted_src[pos] = src[e];
    }
}

// ---------------- aggregation over bf16, dinv-prescaled features
// out[i] = dinv[i]*(sum_e fsc[src] + fsc[i])  (+b2, +row-normalize when FINAL)
// one wave per node, lane = feature (64)
template <bool FINAL>
__global__ __launch_bounds__(256) void k_agg_bf(const unsigned short* __restrict__ fsc,
                                                const float* __restrict__ dinv,
                                                const int* __restrict__ offsets,
                                                const int* __restrict__ sorted_src,
                                                const float* __restrict__ b2,
                                                int N, float* __restrict__ out) {
    int wid = threadIdx.x >> 6;
    int lane = threadIdx.x & 63;
    int i = blockIdx.x * 4 + wid;
    if (i >= N) return;
    int beg = offsets[i], end = offsets[i + 1];
    float acc = bf2f(fsc[(size_t)i * 64 + lane]);  // self-loop term (already dinv-scaled)
    int e = beg;
    for (; e + 3 < end; e += 4) {
        int s0 = sorted_src[e];
        int s1 = sorted_src[e + 1];
        int s2 = sorted_src[e + 2];
        int s3 = sorted_src[e + 3];
        float f0 = bf2f(fsc[(size_t)s0 * 64 + lane]);
        float f1 = bf2f(fsc[(size_t)s1 * 64 + lane]);
        float f2 = bf2f(fsc[(size_t)s2 * 64 + lane]);
        float f3 = bf2f(fsc[(size_t)s3 * 64 + lane]);
        acc += f0 + f1 + f2 + f3;
    }
    for (; e < end; e++) {
        int s0 = sorted_src[e];
        acc += bf2f(fsc[(size_t)s0 * 64 + lane]);
    }
    float di = dinv[i];
    if (!FINAL) {
        out[(size_t)i * 64 + lane] = acc * di;
    } else {
        float z = acc * di + b2[lane];
        float sq = z * z;
#pragma unroll
        for (int m = 32; m >= 1; m >>= 1) sq += __shfl_xor(sq, m, 64);
        float nrm = sqrtf(sq);
        out[(size_t)i * 64 + lane] = z / (nrm + 1e-12f);
    }
}

// ---------------- fused: gsc = bf16( dinv[i] * (relu(z1@W1 + b1) @ W2) )
// 32 rows per block, 256 threads. Register-tiled 4x4 / 4x2.
__global__ __launch_bounds__(256) void k_fused(const float* __restrict__ z1,
                                               const float* __restrict__ W1,
                                               const float* __restrict__ b1,
                                               const float* __restrict__ W2,
                                               const float* __restrict__ dinv,
                                               int N, unsigned short* __restrict__ gsc) {
    __shared__ float W1s[64 * 128];           // 32 KB
    __shared__ unsigned short W2s[128 * 64];  // 16 KB (bf16)
    __shared__ float As[32][68];              // padded (aligned float4 rows, bank-spread)
    __shared__ unsigned short Hs[32][132];    // padded bf16 intermediate
    __shared__ float b1s[128];
    __shared__ float dl[32];

    int t = threadIdx.x;
    int r0blk = blockIdx.x * 32;

    // stage W1 (fp32), W2 (bf16), b1, A rows, dinv
    for (int idx = t; idx < 2048; idx += 256)
        ((float4*)W1s)[idx] = ((const float4*)W1)[idx];
    for (int idx = t; idx < 2048; idx += 256) {
        float4 v = ((const float4*)W2)[idx];
        ushort4 u;
        u.x = f2bf(v.x); u.y = f2bf(v.y); u.z = f2bf(v.z); u.w = f2bf(v.w);
        ((ushort4*)W2s)[idx] = u;
    }
    if (t < 128) b1s[t] = b1[t];
    for (int idx = t; idx < 512; idx += 256) {
        int r = idx >> 4;
        int c4 = idx & 15;
        int row = r0blk + r;
        float4 v = (row < N) ? ((const float4*)z1)[(size_t)row * 16 + c4]
                             : make_float4(0.f, 0.f, 0.f, 0.f);
        *(float4*)&As[r][c4 * 4] = v;
    }
    if (t < 32) dl[t] = (r0blk + t < N) ? dinv[r0blk + t] : 0.f;
    __syncthreads();

    int rg = t >> 5;   // 0..7 (row group of 4)
    int cg = t & 31;   // 0..31
    int r0 = rg * 4;
    int c0 = cg * 4;   // stage-1 column base (128 cols)

    // ---- stage 1: H = relu(A @ W1 + b1), bf16 ----
    float acc[4][4];
#pragma unroll
    for (int j = 0; j < 4; j++)
#pragma unroll
        for (int q = 0; q < 4; q++) acc[j][q] = 0.f;
    for (int k = 0; k < 64; k++) {
        float a0 = As[r0 + 0][k];
        float a1 = As[r0 + 1][k];
        float a2 = As[r0 + 2][k];
        float a3 = As[r0 + 3][k];
        float4 w = *(const float4*)&W1s[k * 128 + c0];
        acc[0][0] = fmaf(a0, w.x, acc[0][0]); acc[0][1] = fmaf(a0, w.y, acc[0][1]);
        acc[0][2] = fmaf(a0, w.z, acc[0][2]); acc[0][3] = fmaf(a0, w.w, acc[0][3]);
        acc[1][0] = fmaf(a1, w.x, acc[1][0]); acc[1][1] = fmaf(a1, w.y, acc[1][1]);
        acc[1][2] = fmaf(a1, w.z, acc[1][2]); acc[1][3] = fmaf(a1, w.w, acc[1][3]);
        acc[2][0] = fmaf(a2, w.x, acc[2][0]); acc[2][1] = fmaf(a2, w.y, acc[2][1]);
        acc[2][2] = fmaf(a2, w.z, acc[2][2]); acc[2][3] = fmaf(a2, w.w, acc[2][3]);
        acc[3][0] = fmaf(a3, w.x, acc[3][0]); acc[3][1] = fmaf(a3, w.y, acc[3][1]);
        acc[3][2] = fmaf(a3, w.z, acc[3][2]); acc[3][3] = fmaf(a3, w.w, acc[3][3]);
    }
#pragma unroll
    for (int j = 0; j < 4; j++) {
        ushort4 hu;
        hu.x = f2bf(fmaxf(acc[j][0] + b1s[c0 + 0], 0.f));
        hu.y = f2bf(fmaxf(acc[j][1] + b1s[c0 + 1], 0.f));
        hu.z = f2bf(fmaxf(acc[j][2] + b1s[c0 + 2], 0.f));
        hu.w = f2bf(fmaxf(acc[j][3] + b1s[c0 + 3], 0.f));
        *(ushort4*)&Hs[r0 + j][c0] = hu;
    }
    __syncthreads();

    // ---- stage 2: G = H @ W2, scale by dinv, emit bf16 ----
    float acc2[4][2];
#pragma unroll
    for (int j = 0; j < 4; j++) { acc2[j][0] = 0.f; acc2[j][1] = 0.f; }
    int c2 = cg * 2;  // stage-2 column base (64 cols)
    for (int k = 0; k < 128; k += 2) {
        ushort2 au0 = *(const ushort2*)&Hs[r0 + 0][k];
        ushort2 au1 = *(const ushort2*)&Hs[r0 + 1][k];
        ushort2 au2 = *(const ushort2*)&Hs[r0 + 2][k];
        ushort2 au3 = *(const ushort2*)&Hs[r0 + 3][k];
        ushort2 w0u = *(const ushort2*)&W2s[k * 64 + c2];
        ushort2 w1u = *(const ushort2*)&W2s[(k + 1) * 64 + c2];
        float wx0 = bf2f(w0u.x), wy0 = bf2f(w0u.y);
        float wx1 = bf2f(w1u.x), wy1 = bf2f(w1u.y);
        float a00 = bf2f(au0.x), a01 = bf2f(au0.y);
        float a10 = bf2f(au1.x), a11 = bf2f(au1.y);
        float a20 = bf2f(au2.x), a21 = bf2f(au2.y);
        float a30 = bf2f(au3.x), a31 = bf2f(au3.y);
        acc2[0][0] = fmaf(a00, wx0, fmaf(a01, wx1, acc2[0][0]));
        acc2[0][1] = fmaf(a00, wy0, fmaf(a01, wy1, acc2[0][1]));
        acc2[1][0] = fmaf(a10, wx0, fmaf(a11, wx1, acc2[1][0]));
        acc2[1][1] = fmaf(a10, wy0, fmaf(a11, wy1, acc2[1][1]));
        acc2[2][0] = fmaf(a20, wx0, fmaf(a21, wx1, acc2[2][0]));
        acc2[2][1] = fmaf(a20, wy0, fmaf(a21, wy1, acc2[2][1]));
        acc2[3][0] = fmaf(a30, wx0, fmaf(a31, wx1, acc2[3][0]));
        acc2[3][1] = fmaf(a30, wy0, fmaf(a31, wy1, acc2[3][1]));
    }
#pragma unroll
    for (int j = 0; j < 4; j++) {
        int row = r0blk + r0 + j;
        if (row < N) {
            float d = dl[r0 + j];
            ushort2 o;
            o.x = f2bf(acc2[j][0] * d);
            o.y = f2bf(acc2[j][1] * d);
            *(ushort2*)&gsc[(size_t)row * 64 + c2] = o;
        }
    }
}

// ---------------- decoder GEMM (64->256) fused with log_softmax
__global__ __launch_bounds__(256) void k_dec(const float* __restrict__ F,
                                             const float* __restrict__ Wd,
                                             const float* __restrict__ bd,
                                             int N, float* __restrict__ out) {
    __shared__ float Wl[64 * 256];  // 64 KB
    __shared__ float bl[256];
    int t = threadIdx.x;
    for (int idx = t; idx < 64 * 256 / 4; idx += 256)
        ((float4*)Wl)[idx] = ((const float4*)Wd)[idx];
    if (t < 256) bl[t] = bd[t];
    __syncthreads();
    int wid = t >> 6, lane = t & 63;
    int nTasks = (N + 3) / 4;
    int stride = gridDim.x * 4;
    for (int task = blockIdx.x * 4 + wid; task < nTasks; task += stride) {
        int r0 = task * 4;
        float v[4];
#pragma unroll
        for (int j = 0; j < 4; j++)
            v[j] = (r0 + j < N) ? F[(size_t)(r0 + j) * 64 + lane] : 0.f;
        float acc[4][4];
#pragma unroll
        for (int j = 0; j < 4; j++)
#pragma unroll
            for (int q = 0; q < 4; q++) acc[j][q] = 0.f;
        for (int k = 0; k < 64; k++) {
            float4 w4 = ((const float4*)Wl)[k * 64 + lane];
#pragma unroll
            for (int j = 0; j < 4; j++) {
                float fk = __shfl(v[j], k, 64);
                acc[j][0] = fmaf(fk, w4.x, acc[j][0]);
                acc[j][1] = fmaf(fk, w4.y, acc[j][1]);
                acc[j][2] = fmaf(fk, w4.z, acc[j][2]);
                acc[j][3] = fmaf(fk, w4.w, acc[j][3]);
            }
        }
        float4 b4 = ((const float4*)bl)[lane];
#pragma unroll
        for (int j = 0; j < 4; j++) {
            int row = r0 + j;
            if (row >= N) break;
            float a0 = acc[j][0] + b4.x;
            float a1 = acc[j][1] + b4.y;
            float a2 = acc[j][2] + b4.z;
            float a3 = acc[j][3] + b4.w;
            float m = fmaxf(fmaxf(a0, a1), fmaxf(a2, a3));
#pragma unroll
            for (int mm = 32; mm >= 1; mm >>= 1) m = fmaxf(m, __shfl_xor(m, mm, 64));
            float s = __expf(a0 - m) + __expf(a1 - m) + __expf(a2 - m) + __expf(a3 - m);
#pragma unroll
            for (int mm = 32; mm >= 1; mm >>= 1) s += __shfl_xor(s, mm, 64);
            float lz = m + __logf(s);
            float4 o = make_float4(a0 - lz, a1 - lz, a2 - lz, a3 - lz);
            ((float4*)out)[(size_t)row * 64 + lane] = o;
        }
    }
}

extern "C" void kernel_launch(void* const* d_in, const int* in_sizes, int n_in,
                              void* d_out, int out_size, void* d_ws, size_t ws_size,
                              hipStream_t stream) {
    const float* x = (const float*)d_in[0];
    const int* ei = (const int*)d_in[1];
    const float* W1 = (const float*)d_in[2];
    const float* b1 = (const float*)d_in[3];
    const float* W2 = (const float*)d_in[4];
    const float* b2 = (const float*)d_in[5];
    const float* Wd = (const float*)d_in[6];
    const float* bd = (const float*)d_in[7];
    int N = in_sizes[0] / 64;
    int E = in_sizes[1] / 2;
    const int* srcIdx = ei;
    const int* dstIdx = ei + E;

    char* w = (char*)d_ws;
    auto alloc = [&](size_t bytes) {
        void* p = (void*)w;
        w += (bytes + 255) & ~(size_t)255;
        return p;
    };
    int* counts = (int*)alloc((size_t)N * 4);
    int* cursor = (int*)alloc((size_t)N * 4);
    int* offsets = (int*)alloc((size_t)(N + 1) * 4);
    int* blockSums = (int*)alloc(4096);
    int* blockOffsets = (int*)alloc(4096);
    int* sorted_src = (int*)alloc((size_t)E * 4);
    float* dinv = (float*)alloc((size_t)N * 4);
    unsigned short* xsc = (unsigned short*)alloc((size_t)N * 64 * 2);
    unsigned short* gsc = (unsigned short*)alloc((size_t)N * 64 * 2);
    float* z1 = (float*)alloc((size_t)N * 64 * 4);
    float* outLogp = (float*)d_out;
    float* outFinal = (float*)d_out + (size_t)N * 256;

    hipMemsetAsync(counts, 0, (size_t)N * 4, stream);
    hipMemsetAsync(cursor, 0, (size_t)N * 4, stream);

    k_count<<<(E + 255) / 256, 256, 0, stream>>>(dstIdx, E, counts);
    k_dinv<<<(N + 255) / 256, 256, 0, stream>>>(counts, N, dinv);
    k_prep<<<(N * 16 + 255) / 256, 256, 0, stream>>>(x, dinv, N, xsc);

    int nb = (N + SCAN_ELEMS - 1) / SCAN_ELEMS;
    k_scan1<<<nb, SCAN_BLOCK, 0, stream>>>(counts, N, offsets, blockSums);
    k_scan2<<<1, SCAN_BLOCK, 0, stream>>>(blockSums, nb, blockOffsets);
    k_scan3<<<(N + 255) / 256, 256, 0, stream>>>(offsets, N, blockOffsets, nb);
    k_scatter<<<(E + 255) / 256, 256, 0, stream>>>(srcIdx, dstIdx, E, offsets, cursor, sorted_src);

    // layer 1: z1 = A_hat-weighted sum of xsc (already dinv-prescaled)
    k_agg_bf<false><<<(N + 3) / 4, 256, 0, stream>>>(xsc, dinv, offsets, sorted_src, nullptr, N, z1);

    // fused MLP: gsc = bf16(dinv .* (relu(z1@W1+b1) @ W2))
    k_fused<<<(N + 31) / 32, 256, 0, stream>>>(z1, W1, b1, W2, dinv, N, gsc);

    // layer 2 aggregation + bias + row-normalize -> final embeddings
    k_agg_bf<true><<<(N + 3) / 4, 256, 0, stream>>>(gsc, dinv, offsets, sorted_src, b2, N, outFinal);

    // decoder + log_softmax
    k_dec<<<2048, 256, 0, stream>>>(outFinal, Wd, bd, N, outLogp);
}